// Round 18
// baseline (923.697 us; speedup 1.0000x reference)
//
#include <hip/hip_runtime.h>
#include <hip/hip_bf16.h>
#include <math.h>

typedef __hip_bfloat16 bf16;
typedef __attribute__((ext_vector_type(8))) short bf16x8_t;   // MFMA A/B frag (4 VGPRs)
typedef __attribute__((ext_vector_type(4))) short bf16x4_t;
typedef __attribute__((ext_vector_type(4))) float f32x4_t;    // MFMA C/D frag

// ---------------- constants ----------------
#define BN_RDENOM 0.9999950000374997f   // 1/sqrt(1+1e-5)
#define EPS_LN 1e-5f
#define ATTN_SCALE 0.17677669529663687f // 1/sqrt(32)
#define S_LEN 1025
#define S_PAD 1152                      // 9*128, for unconditional chunked loads
#define E_DIM 256
#define NHEAD 8
#define HDIM 32
#define MROWS (8 * S_LEN)               // 8200

__device__ __forceinline__ float bf(const bf16 v) { return __bfloat162float(v); }
__device__ __forceinline__ bf16 tobf(float v) { return __float2bfloat16(v); }
__device__ __forceinline__ short bfbits(float v) {
    bf16 t = __float2bfloat16(v); short s; __builtin_memcpy(&s, &t, 2); return s;
}
__device__ __forceinline__ float gelu_exact(float x) {
    return 0.5f * x * (1.0f + erff(x * 0.70710678118654752f));
}

// 16-lane (DPP row) all-reduce via row_ror — VALU speed, no LDS pipe.
#define DPP_ROR(x, N) __int_as_float(__builtin_amdgcn_update_dpp(0, __float_as_int(x), 0x120 + (N), 0xF, 0xF, false))
__device__ __forceinline__ float row_allsum(float x) {
    x = x + DPP_ROR(x, 1);
    x = x + DPP_ROR(x, 2);
    x = x + DPP_ROR(x, 4);
    x = x + DPP_ROR(x, 8);
    return x;
}

// ---------------- weight conversion fp32 -> bf16 ----------------
__global__ __launch_bounds__(256) void cvt_w(const float* __restrict__ src,
    bf16* __restrict__ dst, int n)
{
    int i = (blockIdx.x * 256 + threadIdx.x) * 4;
    if (i >= n) return;
    f32x4_t v = *(const f32x4_t*)(src + i);
    bf16x4_t o;
    #pragma unroll
    for (int j = 0; j < 4; ++j) o[j] = bfbits(v[j]);
    *(bf16x4_t*)((short*)dst + i) = o;
}

// all six weight tensors of one layer into one slot:
// [Wq 64K][Wk 64K][Wv 64K][Wo 64K][W1 256K][W2 256K] = 786432 elems. grid 768.
__global__ __launch_bounds__(256) void cvt_layer(const float* __restrict__ wq,
    const float* __restrict__ wk, const float* __restrict__ wv, const float* __restrict__ wo,
    const float* __restrict__ w1, const float* __restrict__ w2, bf16* __restrict__ dst)
{
    int i = (blockIdx.x * 256 + threadIdx.x) * 4;
    const float* s; int off;
    if (i < 262144) {
        s = (i < 65536) ? wq : (i < 131072) ? wk : (i < 196608) ? wv : wo;
        off = i & 65535;
    } else if (i < 524288) { s = w1; off = i - 262144; }
    else                   { s = w2; off = i - 524288; }
    f32x4_t v = *(const f32x4_t*)(s + off);
    bf16x4_t o;
    #pragma unroll
    for (int j = 0; j < 4; ++j) o[j] = bfbits(v[j]);
    *(bf16x4_t*)((short*)dst + i) = o;
}

// ---------------- conv block 1 ----------------
__global__ __launch_bounds__(256) void conv_sep1(const float* __restrict__ x,
    const float* __restrict__ dw, const float* __restrict__ pw,
    const float* __restrict__ g, const float* __restrict__ bb,
    bf16* __restrict__ out)
{
    __shared__ float xs[70][64];
    __shared__ float dy[32][64];
    __shared__ float pws[64][65];
    __shared__ float dws[64][7];
    int blk = blockIdx.x;
    int tile = blk & 63, b = blk >> 6;
    int t0 = tile * 32;
    int tid = threadIdx.x;
    int tbase = t0 * 2 - 3;
    for (int i = tid; i < 70 * 64; i += 256) {
        int r = i >> 6, c = i & 63;
        int t = tbase + r;
        xs[r][c] = (t >= 0 && t < 4096) ? x[((size_t)b * 4096 + t) * 64 + c] : 0.f;
    }
    for (int i = tid; i < 64 * 7; i += 256) dws[i / 7][i % 7] = dw[i];
    for (int i = tid; i < 64 * 64; i += 256) pws[i >> 6][i & 63] = pw[i];
    __syncthreads();
    for (int i = tid; i < 32 * 64; i += 256) {
        int tl = i >> 6, c = i & 63;
        float s = 0.f;
        #pragma unroll
        for (int j = 0; j < 7; ++j) s += xs[2 * tl + j][c] * dws[c][j];
        dy[tl][c] = s;
    }
    __syncthreads();
    for (int i = tid; i < 32 * 64; i += 256) {
        int tl = i >> 6, o = i & 63;
        float s = 0.f;
        #pragma unroll 8
        for (int c = 0; c < 64; ++c) s += dy[tl][c] * pws[o][c];
        s = s * BN_RDENOM * g[o] + bb[o];
        out[((size_t)(b * 2048 + t0 + tl)) * 64 + o] = tobf(gelu_exact(s));
    }
}

// ---------------- conv block 2 ----------------
__global__ __launch_bounds__(256) void conv_sep2(const bf16* __restrict__ x,
    const float* __restrict__ dw, const float* __restrict__ pw,
    const float* __restrict__ g, const float* __restrict__ bb,
    bf16* __restrict__ out)
{
    __shared__ float xs[70][64];
    __shared__ float dy[32][64];
    __shared__ float pws[128][65];
    __shared__ float dws[64][7];
    int blk = blockIdx.x;
    int tile = blk & 31, b = blk >> 5;
    int t0 = tile * 32;
    int tid = threadIdx.x;
    int tbase = t0 * 2 - 3;
    for (int i = tid; i < 70 * 64; i += 256) {
        int r = i >> 6, c = i & 63;
        int t = tbase + r;
        xs[r][c] = (t >= 0 && t < 2048) ? bf(x[((size_t)b * 2048 + t) * 64 + c]) : 0.f;
    }
    for (int i = tid; i < 64 * 7; i += 256) dws[i / 7][i % 7] = dw[i];
    for (int i = tid; i < 128 * 64; i += 256) pws[i >> 6][i & 63] = pw[i];
    __syncthreads();
    for (int i = tid; i < 32 * 64; i += 256) {
        int tl = i >> 6, c = i & 63;
        float s = 0.f;
        #pragma unroll
        for (int j = 0; j < 7; ++j) s += xs[2 * tl + j][c] * dws[c][j];
        dy[tl][c] = s;
    }
    __syncthreads();
    for (int i = tid; i < 32 * 128; i += 256) {
        int tl = i >> 7, o = i & 127;
        float s = 0.f;
        #pragma unroll 8
        for (int c = 0; c < 64; ++c) s += dy[tl][c] * pws[o][c];
        s = s * BN_RDENOM * g[o] + bb[o];
        out[((size_t)(b * 1024 + t0 + tl)) * 128 + o] = tobf(gelu_exact(s));
    }
}

// ---------------- MFMA GEMM (R12-measured): all-bf16, BK=64, 64x64 tile ----------------
template <int ACT>
__global__ __launch_bounds__(256) void gemm_bf(const bf16* __restrict__ A,
    const bf16* __restrict__ W, const float* __restrict__ bias,
    bf16* __restrict__ C, int M, int N, int K)
{
    __shared__ short As[64 * 72];
    __shared__ short Bs[64 * 72];
    int tid = threadIdx.x;
    int wave = tid >> 6, lane = tid & 63, quad = lane >> 4, l16 = lane & 15;
    int wm = wave & 1, wn = wave >> 1;
    int m0 = blockIdx.x * 64, n0 = blockIdx.y * 64;

    f32x4_t zero4 = {0.f, 0.f, 0.f, 0.f};
    f32x4_t acc[2][2];
    acc[0][0] = zero4; acc[0][1] = zero4; acc[1][0] = zero4; acc[1][1] = zero4;

    int srow = tid >> 2, skc = (tid & 3) * 16;
    for (int k0 = 0; k0 < K; k0 += 64) {
        {
            int m = m0 + srow;
            bf16x8_t a0 = {}, a1 = {};
            if (m < M) {
                a0 = *(const bf16x8_t*)(A + (size_t)m * K + k0 + skc);
                a1 = *(const bf16x8_t*)(A + (size_t)m * K + k0 + skc + 8);
            }
            *(bf16x8_t*)(&As[srow * 72 + skc])     = a0;
            *(bf16x8_t*)(&As[srow * 72 + skc + 8]) = a1;
        }
        {
            const bf16* wp = W + (size_t)(n0 + srow) * K + k0 + skc;
            *(bf16x8_t*)(&Bs[srow * 72 + skc])     = *(const bf16x8_t*)(wp);
            *(bf16x8_t*)(&Bs[srow * 72 + skc + 8]) = *(const bf16x8_t*)(wp + 8);
        }
        __syncthreads();
        #pragma unroll
        for (int ks = 0; ks < 2; ++ks) {
            bf16x8_t a[2], b[2];
            #pragma unroll
            for (int mi = 0; mi < 2; ++mi)
                a[mi] = *(bf16x8_t*)(&As[(wm * 32 + mi * 16 + l16) * 72 + ks * 32 + quad * 8]);
            #pragma unroll
            for (int ni = 0; ni < 2; ++ni)
                b[ni] = *(bf16x8_t*)(&Bs[(wn * 32 + ni * 16 + l16) * 72 + ks * 32 + quad * 8]);
            #pragma unroll
            for (int mi = 0; mi < 2; ++mi)
                #pragma unroll
                for (int ni = 0; ni < 2; ++ni)
                    acc[mi][ni] = __builtin_amdgcn_mfma_f32_16x16x32_bf16(a[mi], b[ni], acc[mi][ni], 0, 0, 0);
        }
        __syncthreads();
    }
    #pragma unroll
    for (int mi = 0; mi < 2; ++mi) {
        #pragma unroll
        for (int ni = 0; ni < 2; ++ni) {
            int col = n0 + wn * 32 + ni * 16 + l16;
            float bv = bias[col];
            #pragma unroll
            for (int r = 0; r < 4; ++r) {
                int row = m0 + wm * 32 + mi * 16 + quad * 4 + r;
                if (row < M) {
                    float v = acc[mi][ni][r] + bv;
                    if (ACT == 1) v = gelu_exact(v);
                    C[(size_t)row * N + col] = tobf(v);
                }
            }
        }
    }
}

// ---------------- MFMA GEMM 128x64 (R11/R12-measured, MLP-up): 4 waves of 64x32, BK=64 ----
template <int ACT>
__global__ __launch_bounds__(256) void gemm_bf128(const bf16* __restrict__ A,
    const bf16* __restrict__ W, const float* __restrict__ bias,
    bf16* __restrict__ C, int M, int N, int K)
{
    __shared__ short As[128 * 72];
    __shared__ short Bs[64 * 72];
    int tid = threadIdx.x;
    int wave = tid >> 6, lane = tid & 63, quad = lane >> 4, l16 = lane & 15;
    int wm = wave & 1, wn = wave >> 1;
    int m0 = blockIdx.x * 128, n0 = blockIdx.y * 64;

    f32x4_t zero4 = {0.f, 0.f, 0.f, 0.f};
    f32x4_t acc[4][2];
    #pragma unroll
    for (int i = 0; i < 4; ++i) { acc[i][0] = zero4; acc[i][1] = zero4; }

    int srow = tid >> 2, skc = (tid & 3) * 16;
    for (int k0 = 0; k0 < K; k0 += 64) {
        #pragma unroll
        for (int p = 0; p < 2; ++p) {
            int row = srow + p * 64;
            int m = m0 + row;
            bf16x8_t a0 = {}, a1 = {};
            if (m < M) {
                a0 = *(const bf16x8_t*)(A + (size_t)m * K + k0 + skc);
                a1 = *(const bf16x8_t*)(A + (size_t)m * K + k0 + skc + 8);
            }
            *(bf16x8_t*)(&As[row * 72 + skc])     = a0;
            *(bf16x8_t*)(&As[row * 72 + skc + 8]) = a1;
        }
        {
            const bf16* wp = W + (size_t)(n0 + srow) * K + k0 + skc;
            *(bf16x8_t*)(&Bs[srow * 72 + skc])     = *(const bf16x8_t*)(wp);
            *(bf16x8_t*)(&Bs[srow * 72 + skc + 8]) = *(const bf16x8_t*)(wp + 8);
        }
        __syncthreads();
        #pragma unroll
        for (int ks = 0; ks < 2; ++ks) {
            bf16x8_t a[4], b[2];
            #pragma unroll
            for (int mi = 0; mi < 4; ++mi)
                a[mi] = *(bf16x8_t*)(&As[(wm * 64 + mi * 16 + l16) * 72 + ks * 32 + quad * 8]);
            #pragma unroll
            for (int ni = 0; ni < 2; ++ni)
                b[ni] = *(bf16x8_t*)(&Bs[(wn * 32 + ni * 16 + l16) * 72 + ks * 32 + quad * 8]);
            #pragma unroll
            for (int mi = 0; mi < 4; ++mi)
                #pragma unroll
                for (int ni = 0; ni < 2; ++ni)
                    acc[mi][ni] = __builtin_amdgcn_mfma_f32_16x16x32_bf16(a[mi], b[ni], acc[mi][ni], 0, 0, 0);
        }
        __syncthreads();
    }
    #pragma unroll
    for (int mi = 0; mi < 4; ++mi) {
        #pragma unroll
        for (int ni = 0; ni < 2; ++ni) {
            int col = n0 + wn * 32 + ni * 16 + l16;
            float bv = bias[col];
            #pragma unroll
            for (int r = 0; r < 4; ++r) {
                int row = m0 + wm * 64 + mi * 16 + quad * 4 + r;
                if (row < M) {
                    float v = acc[mi][ni][r] + bv;
                    if (ACT == 1) v = gelu_exact(v);
                    C[(size_t)row * N + col] = tobf(v);
                }
            }
        }
    }
}

// ---------------- fused QKV GEMM, 128-row shape (R14-measured) + bias + RoPE + Q-scale ----
__global__ __launch_bounds__(256) void gemm_qkv128(const bf16* __restrict__ A,
    const bf16* __restrict__ Wqkv, const float* __restrict__ bq,
    const float* __restrict__ bk, const float* __restrict__ bv,
    bf16* __restrict__ qo, bf16* __restrict__ ko, bf16* __restrict__ vo, int M)
{
    const int K = 256, N = 256;
    __shared__ short As[128 * 72];
    __shared__ short Bs[64 * 72];
    int part = blockIdx.y >> 2;
    int n0 = (blockIdx.y & 3) * 64;
    const bf16* W     = Wqkv + (size_t)part * 65536;
    const float* bias = (part == 0) ? bq : (part == 1) ? bk : bv;
    bf16* C           = (part == 0) ? qo : (part == 1) ? ko : vo;
    bool dorope = (part < 2);
    float oscale = (part == 0) ? ATTN_SCALE : 1.0f;

    int tid = threadIdx.x;
    int wave = tid >> 6, lane = tid & 63, quad = lane >> 4, l16 = lane & 15;
    int wm = wave & 1, wn = wave >> 1;
    int m0 = blockIdx.x * 128;

    f32x4_t zero4 = {0.f, 0.f, 0.f, 0.f};
    f32x4_t acc[4][2];
    #pragma unroll
    for (int i = 0; i < 4; ++i) { acc[i][0] = zero4; acc[i][1] = zero4; }

    int srow = tid >> 2, skc = (tid & 3) * 16;
    for (int k0 = 0; k0 < K; k0 += 64) {
        #pragma unroll
        for (int p = 0; p < 2; ++p) {
            int row = srow + p * 64;
            int m = m0 + row;
            bf16x8_t a0 = {}, a1 = {};
            if (m < M) {
                a0 = *(const bf16x8_t*)(A + (size_t)m * K + k0 + skc);
                a1 = *(const bf16x8_t*)(A + (size_t)m * K + k0 + skc + 8);
            }
            *(bf16x8_t*)(&As[row * 72 + skc])     = a0;
            *(bf16x8_t*)(&As[row * 72 + skc + 8]) = a1;
        }
        {
            const bf16* wp = W + (size_t)(n0 + srow) * K + k0 + skc;
            *(bf16x8_t*)(&Bs[srow * 72 + skc])     = *(const bf16x8_t*)(wp);
            *(bf16x8_t*)(&Bs[srow * 72 + skc + 8]) = *(const bf16x8_t*)(wp + 8);
        }
        __syncthreads();
        #pragma unroll
        for (int ks = 0; ks < 2; ++ks) {
            bf16x8_t a[4], b[2];
            #pragma unroll
            for (int mi = 0; mi < 4; ++mi)
                a[mi] = *(bf16x8_t*)(&As[(wm * 64 + mi * 16 + l16) * 72 + ks * 32 + quad * 8]);
            #pragma unroll
            for (int ni = 0; ni < 2; ++ni)
                b[ni] = *(bf16x8_t*)(&Bs[(wn * 32 + ni * 16 + l16) * 72 + ks * 32 + quad * 8]);
            #pragma unroll
            for (int mi = 0; mi < 4; ++mi)
                #pragma unroll
                for (int ni = 0; ni < 2; ++ni)
                    acc[mi][ni] = __builtin_amdgcn_mfma_f32_16x16x32_bf16(a[mi], b[ni], acc[mi][ni], 0, 0, 0);
        }
        __syncthreads();
    }
    int col0 = n0 + wn * 32 + l16;          // d = l16 within this head
    float b1v = bias[col0], b2v = bias[col0 + 16];
    float invf = powf(10000.f, -(float)l16 * (1.f / 16.f));
    #pragma unroll
    for (int mi = 0; mi < 4; ++mi) {
        #pragma unroll
        for (int r = 0; r < 4; ++r) {
            int row = m0 + wm * 64 + mi * 16 + quad * 4 + r;
            if (row >= M) continue;
            int bb = row / S_LEN, t = row - bb * S_LEN;
            float x1 = acc[mi][0][r] + b1v;
            float x2 = acc[mi][1][r] + b2v;
            if (dorope) {
                float ang = (float)t * invf;
                float sn, cs;
                __sincosf(ang, &sn, &cs);
                float y1 = (x1 * cs - x2 * sn) * oscale;
                float y2 = (x1 * sn + x2 * cs) * oscale;
                x1 = y1; x2 = y2;
            }
            size_t obase = ((size_t)bb * S_PAD + t) * N;
            C[obase + col0]      = tobf(x1);
            C[obase + col0 + 16] = tobf(x2);
        }
    }
}

// ---------------- assemble h ----------------
__global__ __launch_bounds__(256) void assemble_h(const bf16* __restrict__ tmp,
    const float* __restrict__ cls, bf16* __restrict__ h)
{
    int row = blockIdx.x;
    int tid = threadIdx.x;
    int b = row / S_LEN, t = row % S_LEN;
    bf16 v = (t == 0) ? tobf(cls[tid]) : tmp[((size_t)(b * 1024 + t - 1)) * E_DIM + tid];
    h[(size_t)row * E_DIM + tid] = v;
}

// ---------------- MFMA flash attention v11: 128-key chunks (9 barriers) + XCD swizzle ----
// bh = blk & 63 (all 17 q-tiles of one (b,h) on same XCD), qt = blk >> 6.
// Per chunk: stage 128 VT cols, 8 QK MFMA with incremental softmax (sc never >4 VGPR),
// ONE barrier, 4x(P/VT b128 reads + 2 PV MFMA). V reg-prefetch (2x bf16x8).
__global__ __launch_bounds__(256) void attn_mfma(const bf16* __restrict__ Q,
    const bf16* __restrict__ K, const bf16* __restrict__ V, bf16* __restrict__ O)
{
    __shared__ short VTs[2][32 * 136];    // [buf][d][s], stride 136
    __shared__ short Ps[4][16 * 136];     // [wave][q][s], stride 136
    int blk = blockIdx.x;
    int bh = blk & 63;                    // XCD-locality swizzle
    int qt = blk >> 6;
    int hh = bh & 7, b = bh >> 3;
    int tid = threadIdx.x;
    int wave = tid >> 6, lane = tid & 63, quad = lane >> 4, l16 = lane & 15;
    int q0 = qt * 64 + wave * 16;
    const size_t bSp = (size_t)b * S_PAD;
    const size_t bS  = (size_t)b * S_LEN;
    const size_t hoff = (size_t)hh * HDIM;
    const bf16* Qb = Q + bSp * E_DIM + hoff;
    const bf16* Kb = K + bSp * E_DIM + hoff;
    const bf16* Vb = V + bSp * E_DIM + hoff;

    f32x4_t zero4 = {0.f, 0.f, 0.f, 0.f};
    bf16x8_t qfrag = *(const bf16x8_t*)(Qb + (size_t)(q0 + l16) * E_DIM + quad * 8);
    f32x4_t o0 = zero4, o1 = zero4;
    float lsum[4] = {0.f, 0.f, 0.f, 0.f};

    int vs = tid >> 1, vd = (tid & 1) * 16;   // V staging: 128 s-rows x 16 d each
    short* myP = Ps[wave];

    bf16x8_t vpa = *(const bf16x8_t*)(Vb + (size_t)vs * E_DIM + vd);
    bf16x8_t vpb = *(const bf16x8_t*)(Vb + (size_t)vs * E_DIM + vd + 8);

    for (int c = 0; c < 9; ++c) {
        int s0 = c * 128;
        short* VT = VTs[c & 1];
        // stage V^T from prefetched regs
        #pragma unroll
        for (int j = 0; j < 8; ++j) VT[(vd + j) * 136 + vs] = vpa[j];
        #pragma unroll
        for (int j = 0; j < 8; ++j) VT[(vd + 8 + j) * 136 + vs] = vpb[j];
        // prefetch next chunk's V
        if (c < 8) {
            vpa = *(const bf16x8_t*)(Vb + (size_t)(s0 + 128 + vs) * E_DIM + vd);
            vpb = *(const bf16x8_t*)(Vb + (size_t)(s0 + 128 + vs) * E_DIM + vd + 8);
        }
        // QK + incremental softmax (sc transient)
        #pragma unroll
        for (int kk = 0; kk < 8; ++kk) {
            int sbase = s0 + kk * 16;
            bf16x8_t kf = *(const bf16x8_t*)(Kb + (size_t)(sbase + l16) * E_DIM + quad * 8);
            f32x4_t sc = __builtin_amdgcn_mfma_f32_16x16x32_bf16(qfrag, kf, zero4, 0, 0, 0);
            bool ok = (sbase + l16) < S_LEN;
            #pragma unroll
            for (int r = 0; r < 4; ++r) {
                float p = __expf(ok ? sc[r] : -1e30f);
                lsum[r] += p;
                myP[(quad * 4 + r) * 136 + kk * 16 + l16] = bfbits(p);
            }
        }
        __syncthreads();   // VT[buf] staged by all; own P ordered by lgkm
        #pragma unroll
        for (int qtr = 0; qtr < 4; ++qtr) {
            int off = qtr * 32 + quad * 8;
            bf16x8_t pf  = *(bf16x8_t*)(&myP[l16 * 136 + off]);
            bf16x8_t vf0 = *(bf16x8_t*)(&VT[l16 * 136 + off]);
            bf16x8_t vf1 = *(bf16x8_t*)(&VT[(16 + l16) * 136 + off]);
            o0 = __builtin_amdgcn_mfma_f32_16x16x32_bf16(pf, vf0, o0, 0, 0, 0);
            o1 = __builtin_amdgcn_mfma_f32_16x16x32_bf16(pf, vf1, o1, 0, 0, 0);
        }
        // buf reuse (distance 2) ordered by the barrier inside chunk c+1
    }
    #pragma unroll
    for (int r = 0; r < 4; ++r) {
        int qrow = q0 + quad * 4 + r;
        if (qrow < S_LEN) {
            float rs = 1.f / row_allsum(lsum[r]);
            O[(bS + qrow) * E_DIM + hoff + l16]      = tobf(o0[r] * rs);
            O[(bS + qrow) * E_DIM + hoff + 16 + l16] = tobf(o1[r] * rs);
        }
    }
}

// ---------------- residual + layernorm: wave per row ----------------
__global__ __launch_bounds__(256) void ln_kernel(const bf16* __restrict__ X,
    const bf16* __restrict__ R, const float* __restrict__ g,
    const float* __restrict__ b, bf16* __restrict__ out)
{
    int row = blockIdx.x * 4 + (threadIdx.x >> 6);
    int lane = threadIdx.x & 63;
    size_t base = (size_t)row * E_DIM + lane * 4;
    bf16x4_t xv = *(const bf16x4_t*)(X + base);
    float v[4];
    #pragma unroll
    for (int i = 0; i < 4; ++i) { bf16 t; short s = xv[i]; __builtin_memcpy(&t, &s, 2); v[i] = bf(t); }
    if (R) {
        bf16x4_t rv = *(const bf16x4_t*)(R + base);
        #pragma unroll
        for (int i = 0; i < 4; ++i) { bf16 t; short s = rv[i]; __builtin_memcpy(&t, &s, 2); v[i] += bf(t); }
    }
    float s = v[0] + v[1] + v[2] + v[3];
    #pragma unroll
    for (int off = 32; off; off >>= 1) s += __shfl_xor(s, off);
    float mean = s * (1.f / 256.f);
    float var = 0.f;
    #pragma unroll
    for (int i = 0; i < 4; ++i) { v[i] -= mean; var += v[i] * v[i]; }
    #pragma unroll
    for (int off = 32; off; off >>= 1) var += __shfl_xor(var, off);
    float rstd = rsqrtf(var * (1.f / 256.f) + EPS_LN);
    int c = lane * 4;
    bf16x4_t ov;
    #pragma unroll
    for (int i = 0; i < 4; ++i) ov[i] = bfbits(v[i] * rstd * g[c + i] + b[c + i]);
    *(bf16x4_t*)(out + base) = ov;
}

// ---------------- final head ----------------
__global__ __launch_bounds__(256) void ts_kernel(const bf16* __restrict__ H,
    const float* __restrict__ w, const float* __restrict__ tb,
    float* __restrict__ out)
{
    int wid = (blockIdx.x << 2) + (threadIdx.x >> 6);
    int lane = threadIdx.x & 63;
    int b = wid >> 10, t = wid & 1023;
    const bf16* row = H + ((size_t)(b * S_LEN + t + 1)) * E_DIM;
    float acc = 0.f;
    for (int e = lane; e < E_DIM; e += 64) acc += bf(row[e]) * w[e];
    #pragma unroll
    for (int off = 32; off; off >>= 1) acc += __shfl_down(acc, off, 64);
    if (lane == 0) out[wid] = acc + tb[0];
}

// ---------------- host launch ----------------
extern "C" void kernel_launch(void* const* d_in, const int* in_sizes, int n_in,
                              void* d_out, int out_size, void* d_ws, size_t ws_size,
                              hipStream_t stream)
{
    (void)in_sizes; (void)n_in; (void)out_size; (void)ws_size;
    const float* X        = (const float*)d_in[0];
    const float* CONV1_DW = (const float*)d_in[1];
    const float* CONV1_PW = (const float*)d_in[2];
    const float* BN1_G    = (const float*)d_in[3];
    const float* BN1_B    = (const float*)d_in[4];
    const float* CONV2_DW = (const float*)d_in[5];
    const float* CONV2_PW = (const float*)d_in[6];
    const float* BN2_G    = (const float*)d_in[7];
    const float* BN2_B    = (const float*)d_in[8];
    const float* PROJ_W   = (const float*)d_in[9];
    const float* PROJ_B   = (const float*)d_in[10];
    const float* CLS      = (const float*)d_in[11];
    const float* WQ       = (const float*)d_in[12];
    const float* BQ       = (const float*)d_in[13];
    const float* WK       = (const float*)d_in[14];
    const float* BK       = (const float*)d_in[15];
    const float* WV       = (const float*)d_in[16];
    const float* BV       = (const float*)d_in[17];
    const float* WO       = (const float*)d_in[18];
    const float* BO       = (const float*)d_in[19];
    const float* LN1G     = (const float*)d_in[20];
    const float* LN1B     = (const float*)d_in[21];
    const float* W1       = (const float*)d_in[22];
    const float* B1       = (const float*)d_in[23];
    const float* W2       = (const float*)d_in[24];
    const float* B2       = (const float*)d_in[25];
    const float* LN2G     = (const float*)d_in[26];
    const float* LN2B     = (const float*)d_in[27];
    const float* LATW     = (const float*)d_in[28];
    const float* LATB     = (const float*)d_in[29];
    const float* LATNG    = (const float*)d_in[30];
    const float* LATNB    = (const float*)d_in[31];
    const float* TSW      = (const float*)d_in[32];
    const float* TSB      = (const float*)d_in[33];

    const size_t SROW  = (size_t)MROWS * E_DIM;       // 2,099,200
    const size_t SPROW = (size_t)8 * S_PAD * E_DIM;   // 2,359,296 (padded q/k/v)
    bf16* h    = (bf16*)d_ws;
    bf16* bufB = h + SROW;
    bf16* r0   = bufB + SROW;
    bf16* q  = r0;                     // padded stride S_PAD per batch
    bf16* k  = r0 + SPROW;
    bf16* v  = r0 + 2 * SPROW;
    bf16* cx = r0 + 3 * SPROW;         // compact (SROW)
    bf16* wslot = cx + SROW;           // 786,432 elems (layer weights bf16)
    bf16* y1 = r0;
    bf16* y2 = r0 + SROW;
    bf16* mid = r0;                    // MLP hidden 4*SROW <= r0 region size

    conv_sep1<<<dim3(512), dim3(256), 0, stream>>>(X, CONV1_DW, CONV1_PW, BN1_G, BN1_B, y1);
    conv_sep2<<<dim3(256), dim3(256), 0, stream>>>(y1, CONV2_DW, CONV2_PW, BN2_G, BN2_B, y2);
    cvt_w<<<dim3(32), dim3(256), 0, stream>>>(PROJ_W, wslot, 32768);
    gemm_bf<0><<<dim3(128, 4), dim3(256), 0, stream>>>(y2, wslot, PROJ_B, bufB, 8192, 256, 128);
    assemble_h<<<dim3(MROWS), dim3(256), 0, stream>>>(bufB, CLS, h);

    for (int l = 0; l < 6; ++l) {
        cvt_layer<<<dim3(768), dim3(256), 0, stream>>>(
            WQ + (size_t)l * 65536, WK + (size_t)l * 65536, WV + (size_t)l * 65536,
            WO + (size_t)l * 65536, W1 + (size_t)l * 262144, W2 + (size_t)l * 262144, wslot);
        gemm_qkv128<<<dim3(65, 12), dim3(256), 0, stream>>>(h, wslot,
            BQ + l * 256, BK + l * 256, BV + l * 256, q, k, v, MROWS);
        attn_mfma<<<dim3(64 * 17), dim3(256), 0, stream>>>(q, k, v, cx);
        gemm_bf<0><<<dim3(129, 4), dim3(256), 0, stream>>>(cx, wslot + 196608, BO + l * 256, bufB, MROWS, 256, 256);
        ln_kernel<<<dim3(MROWS / 4), dim3(256), 0, stream>>>(h, bufB, LN1G + l * 256, LN1B + l * 256, h);
        gemm_bf128<1><<<dim3(65, 16), dim3(256), 0, stream>>>(h, wslot + 262144, B1 + l * 1024, mid, MROWS, 1024, 256);
        gemm_bf<0><<<dim3(129, 4), dim3(256), 0, stream>>>(mid, wslot + 524288, B2 + l * 256, bufB, MROWS, 256, 1024);
        ln_kernel<<<dim3(MROWS / 4), dim3(256), 0, stream>>>(h, bufB, LN2G + l * 256, LN2B + l * 256, h);
    }

    cvt_w<<<dim3(64), dim3(256), 0, stream>>>(LATW, wslot, 65536);
    gemm_bf<0><<<dim3(129, 4), dim3(256), 0, stream>>>(h, wslot, LATB, bufB, MROWS, 256, 256);
    ln_kernel<<<dim3(MROWS / 4), dim3(256), 0, stream>>>(bufB, nullptr, LATNG, LATNB, r0);
    ts_kernel<<<dim3(2048), dim3(256), 0, stream>>>(r0, TSW, TSB, (float*)d_out);
}

// Round 19
// 859.154 us; speedup vs baseline: 1.0751x; 1.0751x over previous
//
#include <hip/hip_runtime.h>
#include <hip/hip_bf16.h>
#include <math.h>

typedef __hip_bfloat16 bf16;
typedef __attribute__((ext_vector_type(8))) short bf16x8_t;   // MFMA A/B frag (4 VGPRs)
typedef __attribute__((ext_vector_type(4))) short bf16x4_t;
typedef __attribute__((ext_vector_type(4))) float f32x4_t;    // MFMA C/D frag

// ---------------- constants ----------------
#define BN_RDENOM 0.9999950000374997f   // 1/sqrt(1+1e-5)
#define EPS_LN 1e-5f
#define ATTN_SCALE 0.17677669529663687f // 1/sqrt(32)
#define S_LEN 1025
#define S_PAD 1088                      // 17*64, for unconditional chunked loads
#define E_DIM 256
#define NHEAD 8
#define HDIM 32
#define MROWS (8 * S_LEN)               // 8200

__device__ __forceinline__ float bf(const bf16 v) { return __bfloat162float(v); }
__device__ __forceinline__ bf16 tobf(float v) { return __float2bfloat16(v); }
__device__ __forceinline__ short bfbits(float v) {
    bf16 t = __float2bfloat16(v); short s; __builtin_memcpy(&s, &t, 2); return s;
}
__device__ __forceinline__ float gelu_exact(float x) {
    return 0.5f * x * (1.0f + erff(x * 0.70710678118654752f));
}

// 16-lane (DPP row) all-reduce via row_ror — VALU speed, no LDS pipe.
#define DPP_ROR(x, N) __int_as_float(__builtin_amdgcn_update_dpp(0, __float_as_int(x), 0x120 + (N), 0xF, 0xF, false))
__device__ __forceinline__ float row_allsum(float x) {
    x = x + DPP_ROR(x, 1);
    x = x + DPP_ROR(x, 2);
    x = x + DPP_ROR(x, 4);
    x = x + DPP_ROR(x, 8);
    return x;
}

// ---------------- weight conversion fp32 -> bf16 ----------------
__global__ __launch_bounds__(256) void cvt_w(const float* __restrict__ src,
    bf16* __restrict__ dst, int n)
{
    int i = (blockIdx.x * 256 + threadIdx.x) * 4;
    if (i >= n) return;
    f32x4_t v = *(const f32x4_t*)(src + i);
    bf16x4_t o;
    #pragma unroll
    for (int j = 0; j < 4; ++j) o[j] = bfbits(v[j]);
    *(bf16x4_t*)((short*)dst + i) = o;
}

// all six weight tensors of one layer into one slot:
// [Wq 64K][Wk 64K][Wv 64K][Wo 64K][W1 256K][W2 256K] = 786432 elems. grid 768.
__global__ __launch_bounds__(256) void cvt_layer(const float* __restrict__ wq,
    const float* __restrict__ wk, const float* __restrict__ wv, const float* __restrict__ wo,
    const float* __restrict__ w1, const float* __restrict__ w2, bf16* __restrict__ dst)
{
    int i = (blockIdx.x * 256 + threadIdx.x) * 4;
    const float* s; int off;
    if (i < 262144) {
        s = (i < 65536) ? wq : (i < 131072) ? wk : (i < 196608) ? wv : wo;
        off = i & 65535;
    } else if (i < 524288) { s = w1; off = i - 262144; }
    else                   { s = w2; off = i - 524288; }
    f32x4_t v = *(const f32x4_t*)(s + off);
    bf16x4_t o;
    #pragma unroll
    for (int j = 0; j < 4; ++j) o[j] = bfbits(v[j]);
    *(bf16x4_t*)((short*)dst + i) = o;
}

// ---------------- conv block 1 ----------------
__global__ __launch_bounds__(256) void conv_sep1(const float* __restrict__ x,
    const float* __restrict__ dw, const float* __restrict__ pw,
    const float* __restrict__ g, const float* __restrict__ bb,
    bf16* __restrict__ out)
{
    __shared__ float xs[70][64];
    __shared__ float dy[32][64];
    __shared__ float pws[64][65];
    __shared__ float dws[64][7];
    int blk = blockIdx.x;
    int tile = blk & 63, b = blk >> 6;
    int t0 = tile * 32;
    int tid = threadIdx.x;
    int tbase = t0 * 2 - 3;
    for (int i = tid; i < 70 * 64; i += 256) {
        int r = i >> 6, c = i & 63;
        int t = tbase + r;
        xs[r][c] = (t >= 0 && t < 4096) ? x[((size_t)b * 4096 + t) * 64 + c] : 0.f;
    }
    for (int i = tid; i < 64 * 7; i += 256) dws[i / 7][i % 7] = dw[i];
    for (int i = tid; i < 64 * 64; i += 256) pws[i >> 6][i & 63] = pw[i];
    __syncthreads();
    for (int i = tid; i < 32 * 64; i += 256) {
        int tl = i >> 6, c = i & 63;
        float s = 0.f;
        #pragma unroll
        for (int j = 0; j < 7; ++j) s += xs[2 * tl + j][c] * dws[c][j];
        dy[tl][c] = s;
    }
    __syncthreads();
    for (int i = tid; i < 32 * 64; i += 256) {
        int tl = i >> 6, o = i & 63;
        float s = 0.f;
        #pragma unroll 8
        for (int c = 0; c < 64; ++c) s += dy[tl][c] * pws[o][c];
        s = s * BN_RDENOM * g[o] + bb[o];
        out[((size_t)(b * 2048 + t0 + tl)) * 64 + o] = tobf(gelu_exact(s));
    }
}

// ---------------- conv block 2 ----------------
__global__ __launch_bounds__(256) void conv_sep2(const bf16* __restrict__ x,
    const float* __restrict__ dw, const float* __restrict__ pw,
    const float* __restrict__ g, const float* __restrict__ bb,
    bf16* __restrict__ out)
{
    __shared__ float xs[70][64];
    __shared__ float dy[32][64];
    __shared__ float pws[128][65];
    __shared__ float dws[64][7];
    int blk = blockIdx.x;
    int tile = blk & 31, b = blk >> 5;
    int t0 = tile * 32;
    int tid = threadIdx.x;
    int tbase = t0 * 2 - 3;
    for (int i = tid; i < 70 * 64; i += 256) {
        int r = i >> 6, c = i & 63;
        int t = tbase + r;
        xs[r][c] = (t >= 0 && t < 2048) ? bf(x[((size_t)b * 2048 + t) * 64 + c]) : 0.f;
    }
    for (int i = tid; i < 64 * 7; i += 256) dws[i / 7][i % 7] = dw[i];
    for (int i = tid; i < 128 * 64; i += 256) pws[i >> 6][i & 63] = pw[i];
    __syncthreads();
    for (int i = tid; i < 32 * 64; i += 256) {
        int tl = i >> 6, c = i & 63;
        float s = 0.f;
        #pragma unroll
        for (int j = 0; j < 7; ++j) s += xs[2 * tl + j][c] * dws[c][j];
        dy[tl][c] = s;
    }
    __syncthreads();
    for (int i = tid; i < 32 * 128; i += 256) {
        int tl = i >> 7, o = i & 127;
        float s = 0.f;
        #pragma unroll 8
        for (int c = 0; c < 64; ++c) s += dy[tl][c] * pws[o][c];
        s = s * BN_RDENOM * g[o] + bb[o];
        out[((size_t)(b * 1024 + t0 + tl)) * 128 + o] = tobf(gelu_exact(s));
    }
}

// ---------------- MFMA GEMM (R12-measured): all-bf16, BK=64, 64x64 tile ----------------
template <int ACT>
__global__ __launch_bounds__(256) void gemm_bf(const bf16* __restrict__ A,
    const bf16* __restrict__ W, const float* __restrict__ bias,
    bf16* __restrict__ C, int M, int N, int K)
{
    __shared__ short As[64 * 72];
    __shared__ short Bs[64 * 72];
    int tid = threadIdx.x;
    int wave = tid >> 6, lane = tid & 63, quad = lane >> 4, l16 = lane & 15;
    int wm = wave & 1, wn = wave >> 1;
    int m0 = blockIdx.x * 64, n0 = blockIdx.y * 64;

    f32x4_t zero4 = {0.f, 0.f, 0.f, 0.f};
    f32x4_t acc[2][2];
    acc[0][0] = zero4; acc[0][1] = zero4; acc[1][0] = zero4; acc[1][1] = zero4;

    int srow = tid >> 2, skc = (tid & 3) * 16;
    for (int k0 = 0; k0 < K; k0 += 64) {
        {
            int m = m0 + srow;
            bf16x8_t a0 = {}, a1 = {};
            if (m < M) {
                a0 = *(const bf16x8_t*)(A + (size_t)m * K + k0 + skc);
                a1 = *(const bf16x8_t*)(A + (size_t)m * K + k0 + skc + 8);
            }
            *(bf16x8_t*)(&As[srow * 72 + skc])     = a0;
            *(bf16x8_t*)(&As[srow * 72 + skc + 8]) = a1;
        }
        {
            const bf16* wp = W + (size_t)(n0 + srow) * K + k0 + skc;
            *(bf16x8_t*)(&Bs[srow * 72 + skc])     = *(const bf16x8_t*)(wp);
            *(bf16x8_t*)(&Bs[srow * 72 + skc + 8]) = *(const bf16x8_t*)(wp + 8);
        }
        __syncthreads();
        #pragma unroll
        for (int ks = 0; ks < 2; ++ks) {
            bf16x8_t a[2], b[2];
            #pragma unroll
            for (int mi = 0; mi < 2; ++mi)
                a[mi] = *(bf16x8_t*)(&As[(wm * 32 + mi * 16 + l16) * 72 + ks * 32 + quad * 8]);
            #pragma unroll
            for (int ni = 0; ni < 2; ++ni)
                b[ni] = *(bf16x8_t*)(&Bs[(wn * 32 + ni * 16 + l16) * 72 + ks * 32 + quad * 8]);
            #pragma unroll
            for (int mi = 0; mi < 2; ++mi)
                #pragma unroll
                for (int ni = 0; ni < 2; ++ni)
                    acc[mi][ni] = __builtin_amdgcn_mfma_f32_16x16x32_bf16(a[mi], b[ni], acc[mi][ni], 0, 0, 0);
        }
        __syncthreads();
    }
    #pragma unroll
    for (int mi = 0; mi < 2; ++mi) {
        #pragma unroll
        for (int ni = 0; ni < 2; ++ni) {
            int col = n0 + wn * 32 + ni * 16 + l16;
            float bv = bias[col];
            #pragma unroll
            for (int r = 0; r < 4; ++r) {
                int row = m0 + wm * 32 + mi * 16 + quad * 4 + r;
                if (row < M) {
                    float v = acc[mi][ni][r] + bv;
                    if (ACT == 1) v = gelu_exact(v);
                    C[(size_t)row * N + col] = tobf(v);
                }
            }
        }
    }
}

// ---------------- MFMA GEMM 128x64 (R11/R12-measured, MLP-up): 4 waves of 64x32, BK=64 ----
template <int ACT>
__global__ __launch_bounds__(256) void gemm_bf128(const bf16* __restrict__ A,
    const bf16* __restrict__ W, const float* __restrict__ bias,
    bf16* __restrict__ C, int M, int N, int K)
{
    __shared__ short As[128 * 72];
    __shared__ short Bs[64 * 72];
    int tid = threadIdx.x;
    int wave = tid >> 6, lane = tid & 63, quad = lane >> 4, l16 = lane & 15;
    int wm = wave & 1, wn = wave >> 1;
    int m0 = blockIdx.x * 128, n0 = blockIdx.y * 64;

    f32x4_t zero4 = {0.f, 0.f, 0.f, 0.f};
    f32x4_t acc[4][2];
    #pragma unroll
    for (int i = 0; i < 4; ++i) { acc[i][0] = zero4; acc[i][1] = zero4; }

    int srow = tid >> 2, skc = (tid & 3) * 16;
    for (int k0 = 0; k0 < K; k0 += 64) {
        #pragma unroll
        for (int p = 0; p < 2; ++p) {
            int row = srow + p * 64;
            int m = m0 + row;
            bf16x8_t a0 = {}, a1 = {};
            if (m < M) {
                a0 = *(const bf16x8_t*)(A + (size_t)m * K + k0 + skc);
                a1 = *(const bf16x8_t*)(A + (size_t)m * K + k0 + skc + 8);
            }
            *(bf16x8_t*)(&As[row * 72 + skc])     = a0;
            *(bf16x8_t*)(&As[row * 72 + skc + 8]) = a1;
        }
        {
            const bf16* wp = W + (size_t)(n0 + srow) * K + k0 + skc;
            *(bf16x8_t*)(&Bs[srow * 72 + skc])     = *(const bf16x8_t*)(wp);
            *(bf16x8_t*)(&Bs[srow * 72 + skc + 8]) = *(const bf16x8_t*)(wp + 8);
        }
        __syncthreads();
        #pragma unroll
        for (int ks = 0; ks < 2; ++ks) {
            bf16x8_t a[4], b[2];
            #pragma unroll
            for (int mi = 0; mi < 4; ++mi)
                a[mi] = *(bf16x8_t*)(&As[(wm * 64 + mi * 16 + l16) * 72 + ks * 32 + quad * 8]);
            #pragma unroll
            for (int ni = 0; ni < 2; ++ni)
                b[ni] = *(bf16x8_t*)(&Bs[(wn * 32 + ni * 16 + l16) * 72 + ks * 32 + quad * 8]);
            #pragma unroll
            for (int mi = 0; mi < 4; ++mi)
                #pragma unroll
                for (int ni = 0; ni < 2; ++ni)
                    acc[mi][ni] = __builtin_amdgcn_mfma_f32_16x16x32_bf16(a[mi], b[ni], acc[mi][ni], 0, 0, 0);
        }
        __syncthreads();
    }
    #pragma unroll
    for (int mi = 0; mi < 4; ++mi) {
        #pragma unroll
        for (int ni = 0; ni < 2; ++ni) {
            int col = n0 + wn * 32 + ni * 16 + l16;
            float bv = bias[col];
            #pragma unroll
            for (int r = 0; r < 4; ++r) {
                int row = m0 + wm * 64 + mi * 16 + quad * 4 + r;
                if (row < M) {
                    float v = acc[mi][ni][r] + bv;
                    if (ACT == 1) v = gelu_exact(v);
                    C[(size_t)row * N + col] = tobf(v);
                }
            }
        }
    }
}

// ---------------- fused QKV GEMM, 128-row shape (R14-measured) + bias + RoPE + Q-scale ----
__global__ __launch_bounds__(256) void gemm_qkv128(const bf16* __restrict__ A,
    const bf16* __restrict__ Wqkv, const float* __restrict__ bq,
    const float* __restrict__ bk, const float* __restrict__ bv,
    bf16* __restrict__ qo, bf16* __restrict__ ko, bf16* __restrict__ vo, int M)
{
    const int K = 256, N = 256;
    __shared__ short As[128 * 72];
    __shared__ short Bs[64 * 72];
    int part = blockIdx.y >> 2;
    int n0 = (blockIdx.y & 3) * 64;
    const bf16* W     = Wqkv + (size_t)part * 65536;
    const float* bias = (part == 0) ? bq : (part == 1) ? bk : bv;
    bf16* C           = (part == 0) ? qo : (part == 1) ? ko : vo;
    bool dorope = (part < 2);
    float oscale = (part == 0) ? ATTN_SCALE : 1.0f;

    int tid = threadIdx.x;
    int wave = tid >> 6, lane = tid & 63, quad = lane >> 4, l16 = lane & 15;
    int wm = wave & 1, wn = wave >> 1;
    int m0 = blockIdx.x * 128;

    f32x4_t zero4 = {0.f, 0.f, 0.f, 0.f};
    f32x4_t acc[4][2];
    #pragma unroll
    for (int i = 0; i < 4; ++i) { acc[i][0] = zero4; acc[i][1] = zero4; }

    int srow = tid >> 2, skc = (tid & 3) * 16;
    for (int k0 = 0; k0 < K; k0 += 64) {
        #pragma unroll
        for (int p = 0; p < 2; ++p) {
            int row = srow + p * 64;
            int m = m0 + row;
            bf16x8_t a0 = {}, a1 = {};
            if (m < M) {
                a0 = *(const bf16x8_t*)(A + (size_t)m * K + k0 + skc);
                a1 = *(const bf16x8_t*)(A + (size_t)m * K + k0 + skc + 8);
            }
            *(bf16x8_t*)(&As[row * 72 + skc])     = a0;
            *(bf16x8_t*)(&As[row * 72 + skc + 8]) = a1;
        }
        {
            const bf16* wp = W + (size_t)(n0 + srow) * K + k0 + skc;
            *(bf16x8_t*)(&Bs[srow * 72 + skc])     = *(const bf16x8_t*)(wp);
            *(bf16x8_t*)(&Bs[srow * 72 + skc + 8]) = *(const bf16x8_t*)(wp + 8);
        }
        __syncthreads();
        #pragma unroll
        for (int ks = 0; ks < 2; ++ks) {
            bf16x8_t a[4], b[2];
            #pragma unroll
            for (int mi = 0; mi < 4; ++mi)
                a[mi] = *(bf16x8_t*)(&As[(wm * 64 + mi * 16 + l16) * 72 + ks * 32 + quad * 8]);
            #pragma unroll
            for (int ni = 0; ni < 2; ++ni)
                b[ni] = *(bf16x8_t*)(&Bs[(wn * 32 + ni * 16 + l16) * 72 + ks * 32 + quad * 8]);
            #pragma unroll
            for (int mi = 0; mi < 4; ++mi)
                #pragma unroll
                for (int ni = 0; ni < 2; ++ni)
                    acc[mi][ni] = __builtin_amdgcn_mfma_f32_16x16x32_bf16(a[mi], b[ni], acc[mi][ni], 0, 0, 0);
        }
        __syncthreads();
    }
    int col0 = n0 + wn * 32 + l16;          // d = l16 within this head
    float b1v = bias[col0], b2v = bias[col0 + 16];
    float invf = powf(10000.f, -(float)l16 * (1.f / 16.f));
    #pragma unroll
    for (int mi = 0; mi < 4; ++mi) {
        #pragma unroll
        for (int r = 0; r < 4; ++r) {
            int row = m0 + wm * 64 + mi * 16 + quad * 4 + r;
            if (row >= M) continue;
            int bb = row / S_LEN, t = row - bb * S_LEN;
            float x1 = acc[mi][0][r] + b1v;
            float x2 = acc[mi][1][r] + b2v;
            if (dorope) {
                float ang = (float)t * invf;
                float sn, cs;
                __sincosf(ang, &sn, &cs);
                float y1 = (x1 * cs - x2 * sn) * oscale;
                float y2 = (x1 * sn + x2 * cs) * oscale;
                x1 = y1; x2 = y2;
            }
            size_t obase = ((size_t)bb * S_PAD + t) * N;
            C[obase + col0]      = tobf(x1);
            C[obase + col0 + 16] = tobf(x2);
        }
    }
}

// ---------------- assemble h ----------------
__global__ __launch_bounds__(256) void assemble_h(const bf16* __restrict__ tmp,
    const float* __restrict__ cls, bf16* __restrict__ h)
{
    int row = blockIdx.x;
    int tid = threadIdx.x;
    int b = row / S_LEN, t = row % S_LEN;
    bf16 v = (t == 0) ? tobf(cls[tid]) : tmp[((size_t)(b * 1024 + t - 1)) * E_DIM + tid];
    h[(size_t)row * E_DIM + tid] = v;
}

// ---------------- MFMA flash attention (R17-measured ~48.9 us): 64-key chunks + XCD swizzle ----
// bh = blk & 63: all 17 q-tile blocks of one (b,h) share blk mod 8 -> same XCD ->
// K/V L2-resident per XCD (FETCH 39->13 MB measured). Deferred lsum, V reg-prefetch,
// ONE barrier per chunk, wave-private P.
__global__ __launch_bounds__(256) void attn_mfma(const bf16* __restrict__ Q,
    const bf16* __restrict__ K, const bf16* __restrict__ V, bf16* __restrict__ O)
{
    __shared__ short VTs[2][32 * 72];     // [buf][d][s], stride 72
    __shared__ short Ps[4][16 * 72];      // [wave][q][s], stride 72
    int blk = blockIdx.x;
    int bh = blk & 63;                    // XCD-locality swizzle
    int qt = blk >> 6;
    int hh = bh & 7, b = bh >> 3;
    int tid = threadIdx.x;
    int wave = tid >> 6, lane = tid & 63, quad = lane >> 4, l16 = lane & 15;
    int q0 = qt * 64 + wave * 16;
    const size_t bSp = (size_t)b * S_PAD;
    const size_t bS  = (size_t)b * S_LEN;
    const size_t hoff = (size_t)hh * HDIM;
    const bf16* Qb = Q + bSp * E_DIM + hoff;
    const bf16* Kb = K + bSp * E_DIM + hoff;
    const bf16* Vb = V + bSp * E_DIM + hoff;

    f32x4_t zero4 = {0.f, 0.f, 0.f, 0.f};
    bf16x8_t qfrag = *(const bf16x8_t*)(Qb + (size_t)(q0 + l16) * E_DIM + quad * 8);
    f32x4_t o0 = zero4, o1 = zero4;
    float lsum[4] = {0.f, 0.f, 0.f, 0.f};

    int vs = tid >> 2, vd = (tid & 3) * 8;   // V staging: 64 s-rows x 32 d
    short* myP = Ps[wave];

    bf16x8_t vpre = *(const bf16x8_t*)(Vb + (size_t)vs * E_DIM + vd);

    for (int c = 0; c < 17; ++c) {
        int s0 = c * 64;
        short* VT = VTs[c & 1];
        #pragma unroll
        for (int j = 0; j < 8; ++j) VT[(vd + j) * 72 + vs] = vpre[j];
        if (c < 16)
            vpre = *(const bf16x8_t*)(Vb + (size_t)(s0 + 64 + vs) * E_DIM + vd);
        f32x4_t sc[4];
        #pragma unroll
        for (int kk = 0; kk < 4; ++kk) {
            bf16x8_t kf = *(const bf16x8_t*)(Kb + (size_t)(s0 + kk * 16 + l16) * E_DIM + quad * 8);
            sc[kk] = __builtin_amdgcn_mfma_f32_16x16x32_bf16(qfrag, kf, zero4, 0, 0, 0);
        }
        #pragma unroll
        for (int r = 0; r < 4; ++r) {
            float ps = 0.f;
            #pragma unroll
            for (int kk = 0; kk < 4; ++kk) {
                int s = s0 + kk * 16 + l16;
                float raw = (s < S_LEN) ? sc[kk][r] : -1e30f;
                float p = __expf(raw);
                ps += p;
                myP[(quad * 4 + r) * 72 + kk * 16 + l16] = bfbits(p);
            }
            lsum[r] += ps;
        }
        __syncthreads();
        #pragma unroll
        for (int half = 0; half < 2; ++half) {
            int off = half * 32 + quad * 8;
            bf16x8_t pf  = *(bf16x8_t*)(&myP[l16 * 72 + off]);
            bf16x8_t vf0 = *(bf16x8_t*)(&VT[l16 * 72 + off]);
            bf16x8_t vf1 = *(bf16x8_t*)(&VT[(16 + l16) * 72 + off]);
            o0 = __builtin_amdgcn_mfma_f32_16x16x32_bf16(pf, vf0, o0, 0, 0, 0);
            o1 = __builtin_amdgcn_mfma_f32_16x16x32_bf16(pf, vf1, o1, 0, 0, 0);
        }
    }
    #pragma unroll
    for (int r = 0; r < 4; ++r) {
        int qrow = q0 + quad * 4 + r;
        if (qrow < S_LEN) {
            float rs = 1.f / row_allsum(lsum[r]);
            O[(bS + qrow) * E_DIM + hoff + l16]      = tobf(o0[r] * rs);
            O[(bS + qrow) * E_DIM + hoff + 16 + l16] = tobf(o1[r] * rs);
        }
    }
}

// ---------------- residual + layernorm: wave per row ----------------
__global__ __launch_bounds__(256) void ln_kernel(const bf16* __restrict__ X,
    const bf16* __restrict__ R, const float* __restrict__ g,
    const float* __restrict__ b, bf16* __restrict__ out)
{
    int row = blockIdx.x * 4 + (threadIdx.x >> 6);
    int lane = threadIdx.x & 63;
    size_t base = (size_t)row * E_DIM + lane * 4;
    bf16x4_t xv = *(const bf16x4_t*)(X + base);
    float v[4];
    #pragma unroll
    for (int i = 0; i < 4; ++i) { bf16 t; short s = xv[i]; __builtin_memcpy(&t, &s, 2); v[i] = bf(t); }
    if (R) {
        bf16x4_t rv = *(const bf16x4_t*)(R + base);
        #pragma unroll
        for (int i = 0; i < 4; ++i) { bf16 t; short s = rv[i]; __builtin_memcpy(&t, &s, 2); v[i] += bf(t); }
    }
    float s = v[0] + v[1] + v[2] + v[3];
    #pragma unroll
    for (int off = 32; off; off >>= 1) s += __shfl_xor(s, off);
    float mean = s * (1.f / 256.f);
    float var = 0.f;
    #pragma unroll
    for (int i = 0; i < 4; ++i) { v[i] -= mean; var += v[i] * v[i]; }
    #pragma unroll
    for (int off = 32; off; off >>= 1) var += __shfl_xor(var, off);
    float rstd = rsqrtf(var * (1.f / 256.f) + EPS_LN);
    int c = lane * 4;
    bf16x4_t ov;
    #pragma unroll
    for (int i = 0; i < 4; ++i) ov[i] = bfbits(v[i] * rstd * g[c + i] + b[c + i]);
    *(bf16x4_t*)(out + base) = ov;
}

// ---------------- final head ----------------
__global__ __launch_bounds__(256) void ts_kernel(const bf16* __restrict__ H,
    const float* __restrict__ w, const float* __restrict__ tb,
    float* __restrict__ out)
{
    int wid = (blockIdx.x << 2) + (threadIdx.x >> 6);
    int lane = threadIdx.x & 63;
    int b = wid >> 10, t = wid & 1023;
    const bf16* row = H + ((size_t)(b * S_LEN + t + 1)) * E_DIM;
    float acc = 0.f;
    for (int e = lane; e < E_DIM; e += 64) acc += bf(row[e]) * w[e];
    #pragma unroll
    for (int off = 32; off; off >>= 1) acc += __shfl_down(acc, off, 64);
    if (lane == 0) out[wid] = acc + tb[0];
}

// ---------------- host launch ----------------
extern "C" void kernel_launch(void* const* d_in, const int* in_sizes, int n_in,
                              void* d_out, int out_size, void* d_ws, size_t ws_size,
                              hipStream_t stream)
{
    (void)in_sizes; (void)n_in; (void)out_size; (void)ws_size;
    const float* X        = (const float*)d_in[0];
    const float* CONV1_DW = (const float*)d_in[1];
    const float* CONV1_PW = (const float*)d_in[2];
    const float* BN1_G    = (const float*)d_in[3];
    const float* BN1_B    = (const float*)d_in[4];
    const float* CONV2_DW = (const float*)d_in[5];
    const float* CONV2_PW = (const float*)d_in[6];
    const float* BN2_G    = (const float*)d_in[7];
    const float* BN2_B    = (const float*)d_in[8];
    const float* PROJ_W   = (const float*)d_in[9];
    const float* PROJ_B   = (const float*)d_in[10];
    const float* CLS      = (const float*)d_in[11];
    const float* WQ       = (const float*)d_in[12];
    const float* BQ       = (const float*)d_in[13];
    const float* WK       = (const float*)d_in[14];
    const float* BK       = (const float*)d_in[15];
    const float* WV       = (const float*)d_in[16];
    const float* BV       = (const float*)d_in[17];
    const float* WO       = (const float*)d_in[18];
    const float* BO       = (const float*)d_in[19];
    const float* LN1G     = (const float*)d_in[20];
    const float* LN1B     = (const float*)d_in[21];
    const float* W1       = (const float*)d_in[22];
    const float* B1       = (const float*)d_in[23];
    const float* W2       = (const float*)d_in[24];
    const float* B2       = (const float*)d_in[25];
    const float* LN2G     = (const float*)d_in[26];
    const float* LN2B     = (const float*)d_in[27];
    const float* LATW     = (const float*)d_in[28];
    const float* LATB     = (const float*)d_in[29];
    const float* LATNG    = (const float*)d_in[30];
    const float* LATNB    = (const float*)d_in[31];
    const float* TSW      = (const float*)d_in[32];
    const float* TSB      = (const float*)d_in[33];

    const size_t SROW  = (size_t)MROWS * E_DIM;       // 2,099,200
    const size_t SPROW = (size_t)8 * S_PAD * E_DIM;   // 2,228,224 (padded q/k/v)
    bf16* h    = (bf16*)d_ws;
    bf16* bufB = h + SROW;
    bf16* r0   = bufB + SROW;
    bf16* q  = r0;                     // padded stride S_PAD per batch
    bf16* k  = r0 + SPROW;
    bf16* v  = r0 + 2 * SPROW;
    bf16* cx = r0 + 3 * SPROW;         // compact (SROW)
    bf16* wslot = cx + SROW;           // 786,432 elems (layer weights bf16)
    bf16* y1 = r0;
    bf16* y2 = r0 + SROW;
    bf16* mid = r0;                    // MLP hidden 4*SROW <= r0 region size

    conv_sep1<<<dim3(512), dim3(256), 0, stream>>>(X, CONV1_DW, CONV1_PW, BN1_G, BN1_B, y1);
    conv_sep2<<<dim3(256), dim3(256), 0, stream>>>(y1, CONV2_DW, CONV2_PW, BN2_G, BN2_B, y2);
    cvt_w<<<dim3(32), dim3(256), 0, stream>>>(PROJ_W, wslot, 32768);
    gemm_bf<0><<<dim3(128, 4), dim3(256), 0, stream>>>(y2, wslot, PROJ_B, bufB, 8192, 256, 128);
    assemble_h<<<dim3(MROWS), dim3(256), 0, stream>>>(bufB, CLS, h);

    for (int l = 0; l < 6; ++l) {
        cvt_layer<<<dim3(768), dim3(256), 0, stream>>>(
            WQ + (size_t)l * 65536, WK + (size_t)l * 65536, WV + (size_t)l * 65536,
            WO + (size_t)l * 65536, W1 + (size_t)l * 262144, W2 + (size_t)l * 262144, wslot);
        gemm_qkv128<<<dim3(65, 12), dim3(256), 0, stream>>>(h, wslot,
            BQ + l * 256, BK + l * 256, BV + l * 256, q, k, v, MROWS);
        attn_mfma<<<dim3(64 * 17), dim3(256), 0, stream>>>(q, k, v, cx);
        gemm_bf<0><<<dim3(129, 4), dim3(256), 0, stream>>>(cx, wslot + 196608, BO + l * 256, bufB, MROWS, 256, 256);
        ln_kernel<<<dim3(MROWS / 4), dim3(256), 0, stream>>>(h, bufB, LN1G + l * 256, LN1B + l * 256, h);
        gemm_bf128<1><<<dim3(65, 16), dim3(256), 0, stream>>>(h, wslot + 262144, B1 + l * 1024, mid, MROWS, 1024, 256);
        gemm_bf<0><<<dim3(129, 4), dim3(256), 0, stream>>>(mid, wslot + 524288, B2 + l * 256, bufB, MROWS, 256, 1024);
        ln_kernel<<<dim3(MROWS / 4), dim3(256), 0, stream>>>(h, bufB, LN2G + l * 256, LN2B + l * 256, h);
    }

    cvt_w<<<dim3(64), dim3(256), 0, stream>>>(LATW, wslot, 65536);
    gemm_bf<0><<<dim3(129, 4), dim3(256), 0, stream>>>(h, wslot, LATB, bufB, MROWS, 256, 256);
    ln_kernel<<<dim3(MROWS / 4), dim3(256), 0, stream>>>(bufB, nullptr, LATNG, LATNB, r0);
    ts_kernel<<<dim3(2048), dim3(256), 0, stream>>>(r0, TSW, TSB, (float*)d_out);
}

// Round 20
// 835.108 us; speedup vs baseline: 1.1061x; 1.0288x over previous
//
#include <hip/hip_runtime.h>
#include <hip/hip_bf16.h>
#include <math.h>

typedef __hip_bfloat16 bf16;
typedef __attribute__((ext_vector_type(8))) short bf16x8_t;   // MFMA A/B frag (4 VGPRs)
typedef __attribute__((ext_vector_type(4))) short bf16x4_t;
typedef __attribute__((ext_vector_type(4))) float f32x4_t;    // MFMA C/D frag

// ---------------- constants ----------------
#define BN_RDENOM 0.9999950000374997f   // 1/sqrt(1+1e-5)
#define EPS_LN 1e-5f
#define ATTN_SCALE 0.17677669529663687f // 1/sqrt(32)
#define S_LEN 1025
#define S_PAD 1088                      // 17*64, for unconditional chunked loads
#define E_DIM 256
#define NHEAD 8
#define HDIM 32
#define MROWS (8 * S_LEN)               // 8200
#define WSLOT 786432                    // bf16 elems per layer weight slot

__device__ __forceinline__ float bf(const bf16 v) { return __bfloat162float(v); }
__device__ __forceinline__ bf16 tobf(float v) { return __float2bfloat16(v); }
__device__ __forceinline__ short bfbits(float v) {
    bf16 t = __float2bfloat16(v); short s; __builtin_memcpy(&s, &t, 2); return s;
}
__device__ __forceinline__ float gelu_exact(float x) {
    return 0.5f * x * (1.0f + erff(x * 0.70710678118654752f));
}

// 16-lane (DPP row) all-reduce via row_ror — VALU speed, no LDS pipe.
#define DPP_ROR(x, N) __int_as_float(__builtin_amdgcn_update_dpp(0, __float_as_int(x), 0x120 + (N), 0xF, 0xF, false))
__device__ __forceinline__ float row_allsum(float x) {
    x = x + DPP_ROR(x, 1);
    x = x + DPP_ROR(x, 2);
    x = x + DPP_ROR(x, 4);
    x = x + DPP_ROR(x, 8);
    return x;
}

// ---------------- weight conversion fp32 -> bf16 ----------------
__global__ __launch_bounds__(256) void cvt_w(const float* __restrict__ src,
    bf16* __restrict__ dst, int n)
{
    int i = (blockIdx.x * 256 + threadIdx.x) * 4;
    if (i >= n) return;
    f32x4_t v = *(const f32x4_t*)(src + i);
    bf16x4_t o;
    #pragma unroll
    for (int j = 0; j < 4; ++j) o[j] = bfbits(v[j]);
    *(bf16x4_t*)((short*)dst + i) = o;
}

// all six weight tensors of one layer into one slot, ALL LAYERS in one dispatch:
// grid (768, 6); blockIdx.y = layer. [Wq 64K][Wk 64K][Wv 64K][Wo 64K][W1 256K][W2 256K].
__global__ __launch_bounds__(256) void cvt_layer6(const float* __restrict__ wq,
    const float* __restrict__ wk, const float* __restrict__ wv, const float* __restrict__ wo,
    const float* __restrict__ w1, const float* __restrict__ w2, bf16* __restrict__ dst)
{
    int l = blockIdx.y;
    int i = (blockIdx.x * 256 + threadIdx.x) * 4;
    const float* s; int off;
    if (i < 262144) {
        s = (i < 65536) ? wq : (i < 131072) ? wk : (i < 196608) ? wv : wo;
        s += (size_t)l * 65536;
        off = i & 65535;
    } else if (i < 524288) { s = w1 + (size_t)l * 262144; off = i - 262144; }
    else                   { s = w2 + (size_t)l * 262144; off = i - 524288; }
    f32x4_t v = *(const f32x4_t*)(s + off);
    bf16x4_t o;
    #pragma unroll
    for (int j = 0; j < 4; ++j) o[j] = bfbits(v[j]);
    *(bf16x4_t*)((short*)dst + (size_t)l * WSLOT + i) = o;
}

// ---------------- conv block 1 ----------------
__global__ __launch_bounds__(256) void conv_sep1(const float* __restrict__ x,
    const float* __restrict__ dw, const float* __restrict__ pw,
    const float* __restrict__ g, const float* __restrict__ bb,
    bf16* __restrict__ out)
{
    __shared__ float xs[70][64];
    __shared__ float dy[32][64];
    __shared__ float pws[64][65];
    __shared__ float dws[64][7];
    int blk = blockIdx.x;
    int tile = blk & 63, b = blk >> 6;
    int t0 = tile * 32;
    int tid = threadIdx.x;
    int tbase = t0 * 2 - 3;
    for (int i = tid; i < 70 * 64; i += 256) {
        int r = i >> 6, c = i & 63;
        int t = tbase + r;
        xs[r][c] = (t >= 0 && t < 4096) ? x[((size_t)b * 4096 + t) * 64 + c] : 0.f;
    }
    for (int i = tid; i < 64 * 7; i += 256) dws[i / 7][i % 7] = dw[i];
    for (int i = tid; i < 64 * 64; i += 256) pws[i >> 6][i & 63] = pw[i];
    __syncthreads();
    for (int i = tid; i < 32 * 64; i += 256) {
        int tl = i >> 6, c = i & 63;
        float s = 0.f;
        #pragma unroll
        for (int j = 0; j < 7; ++j) s += xs[2 * tl + j][c] * dws[c][j];
        dy[tl][c] = s;
    }
    __syncthreads();
    for (int i = tid; i < 32 * 64; i += 256) {
        int tl = i >> 6, o = i & 63;
        float s = 0.f;
        #pragma unroll 8
        for (int c = 0; c < 64; ++c) s += dy[tl][c] * pws[o][c];
        s = s * BN_RDENOM * g[o] + bb[o];
        out[((size_t)(b * 2048 + t0 + tl)) * 64 + o] = tobf(gelu_exact(s));
    }
}

// ---------------- conv block 2 ----------------
__global__ __launch_bounds__(256) void conv_sep2(const bf16* __restrict__ x,
    const float* __restrict__ dw, const float* __restrict__ pw,
    const float* __restrict__ g, const float* __restrict__ bb,
    bf16* __restrict__ out)
{
    __shared__ float xs[70][64];
    __shared__ float dy[32][64];
    __shared__ float pws[128][65];
    __shared__ float dws[64][7];
    int blk = blockIdx.x;
    int tile = blk & 31, b = blk >> 5;
    int t0 = tile * 32;
    int tid = threadIdx.x;
    int tbase = t0 * 2 - 3;
    for (int i = tid; i < 70 * 64; i += 256) {
        int r = i >> 6, c = i & 63;
        int t = tbase + r;
        xs[r][c] = (t >= 0 && t < 2048) ? bf(x[((size_t)b * 2048 + t) * 64 + c]) : 0.f;
    }
    for (int i = tid; i < 64 * 7; i += 256) dws[i / 7][i % 7] = dw[i];
    for (int i = tid; i < 128 * 64; i += 256) pws[i >> 6][i & 63] = pw[i];
    __syncthreads();
    for (int i = tid; i < 32 * 64; i += 256) {
        int tl = i >> 6, c = i & 63;
        float s = 0.f;
        #pragma unroll
        for (int j = 0; j < 7; ++j) s += xs[2 * tl + j][c] * dws[c][j];
        dy[tl][c] = s;
    }
    __syncthreads();
    for (int i = tid; i < 32 * 128; i += 256) {
        int tl = i >> 7, o = i & 127;
        float s = 0.f;
        #pragma unroll 8
        for (int c = 0; c < 64; ++c) s += dy[tl][c] * pws[o][c];
        s = s * BN_RDENOM * g[o] + bb[o];
        out[((size_t)(b * 1024 + t0 + tl)) * 128 + o] = tobf(gelu_exact(s));
    }
}

// ---------------- MFMA GEMM (R12-measured): all-bf16, BK=64, 64x64 tile ----------------
template <int ACT>
__global__ __launch_bounds__(256) void gemm_bf(const bf16* __restrict__ A,
    const bf16* __restrict__ W, const float* __restrict__ bias,
    bf16* __restrict__ C, int M, int N, int K)
{
    __shared__ short As[64 * 72];
    __shared__ short Bs[64 * 72];
    int tid = threadIdx.x;
    int wave = tid >> 6, lane = tid & 63, quad = lane >> 4, l16 = lane & 15;
    int wm = wave & 1, wn = wave >> 1;
    int m0 = blockIdx.x * 64, n0 = blockIdx.y * 64;

    f32x4_t zero4 = {0.f, 0.f, 0.f, 0.f};
    f32x4_t acc[2][2];
    acc[0][0] = zero4; acc[0][1] = zero4; acc[1][0] = zero4; acc[1][1] = zero4;

    int srow = tid >> 2, skc = (tid & 3) * 16;
    for (int k0 = 0; k0 < K; k0 += 64) {
        {
            int m = m0 + srow;
            bf16x8_t a0 = {}, a1 = {};
            if (m < M) {
                a0 = *(const bf16x8_t*)(A + (size_t)m * K + k0 + skc);
                a1 = *(const bf16x8_t*)(A + (size_t)m * K + k0 + skc + 8);
            }
            *(bf16x8_t*)(&As[srow * 72 + skc])     = a0;
            *(bf16x8_t*)(&As[srow * 72 + skc + 8]) = a1;
        }
        {
            const bf16* wp = W + (size_t)(n0 + srow) * K + k0 + skc;
            *(bf16x8_t*)(&Bs[srow * 72 + skc])     = *(const bf16x8_t*)(wp);
            *(bf16x8_t*)(&Bs[srow * 72 + skc + 8]) = *(const bf16x8_t*)(wp + 8);
        }
        __syncthreads();
        #pragma unroll
        for (int ks = 0; ks < 2; ++ks) {
            bf16x8_t a[2], b[2];
            #pragma unroll
            for (int mi = 0; mi < 2; ++mi)
                a[mi] = *(bf16x8_t*)(&As[(wm * 32 + mi * 16 + l16) * 72 + ks * 32 + quad * 8]);
            #pragma unroll
            for (int ni = 0; ni < 2; ++ni)
                b[ni] = *(bf16x8_t*)(&Bs[(wn * 32 + ni * 16 + l16) * 72 + ks * 32 + quad * 8]);
            #pragma unroll
            for (int mi = 0; mi < 2; ++mi)
                #pragma unroll
                for (int ni = 0; ni < 2; ++ni)
                    acc[mi][ni] = __builtin_amdgcn_mfma_f32_16x16x32_bf16(a[mi], b[ni], acc[mi][ni], 0, 0, 0);
        }
        __syncthreads();
    }
    #pragma unroll
    for (int mi = 0; mi < 2; ++mi) {
        #pragma unroll
        for (int ni = 0; ni < 2; ++ni) {
            int col = n0 + wn * 32 + ni * 16 + l16;
            float bv = bias[col];
            #pragma unroll
            for (int r = 0; r < 4; ++r) {
                int row = m0 + wm * 32 + mi * 16 + quad * 4 + r;
                if (row < M) {
                    float v = acc[mi][ni][r] + bv;
                    if (ACT == 1) v = gelu_exact(v);
                    C[(size_t)row * N + col] = tobf(v);
                }
            }
        }
    }
}

// ---------------- MFMA GEMM 128x64 (R11/R12-measured, MLP-up): 4 waves of 64x32, BK=64 ----
template <int ACT>
__global__ __launch_bounds__(256) void gemm_bf128(const bf16* __restrict__ A,
    const bf16* __restrict__ W, const float* __restrict__ bias,
    bf16* __restrict__ C, int M, int N, int K)
{
    __shared__ short As[128 * 72];
    __shared__ short Bs[64 * 72];
    int tid = threadIdx.x;
    int wave = tid >> 6, lane = tid & 63, quad = lane >> 4, l16 = lane & 15;
    int wm = wave & 1, wn = wave >> 1;
    int m0 = blockIdx.x * 128, n0 = blockIdx.y * 64;

    f32x4_t zero4 = {0.f, 0.f, 0.f, 0.f};
    f32x4_t acc[4][2];
    #pragma unroll
    for (int i = 0; i < 4; ++i) { acc[i][0] = zero4; acc[i][1] = zero4; }

    int srow = tid >> 2, skc = (tid & 3) * 16;
    for (int k0 = 0; k0 < K; k0 += 64) {
        #pragma unroll
        for (int p = 0; p < 2; ++p) {
            int row = srow + p * 64;
            int m = m0 + row;
            bf16x8_t a0 = {}, a1 = {};
            if (m < M) {
                a0 = *(const bf16x8_t*)(A + (size_t)m * K + k0 + skc);
                a1 = *(const bf16x8_t*)(A + (size_t)m * K + k0 + skc + 8);
            }
            *(bf16x8_t*)(&As[row * 72 + skc])     = a0;
            *(bf16x8_t*)(&As[row * 72 + skc + 8]) = a1;
        }
        {
            const bf16* wp = W + (size_t)(n0 + srow) * K + k0 + skc;
            *(bf16x8_t*)(&Bs[srow * 72 + skc])     = *(const bf16x8_t*)(wp);
            *(bf16x8_t*)(&Bs[srow * 72 + skc + 8]) = *(const bf16x8_t*)(wp + 8);
        }
        __syncthreads();
        #pragma unroll
        for (int ks = 0; ks < 2; ++ks) {
            bf16x8_t a[4], b[2];
            #pragma unroll
            for (int mi = 0; mi < 4; ++mi)
                a[mi] = *(bf16x8_t*)(&As[(wm * 64 + mi * 16 + l16) * 72 + ks * 32 + quad * 8]);
            #pragma unroll
            for (int ni = 0; ni < 2; ++ni)
                b[ni] = *(bf16x8_t*)(&Bs[(wn * 32 + ni * 16 + l16) * 72 + ks * 32 + quad * 8]);
            #pragma unroll
            for (int mi = 0; mi < 4; ++mi)
                #pragma unroll
                for (int ni = 0; ni < 2; ++ni)
                    acc[mi][ni] = __builtin_amdgcn_mfma_f32_16x16x32_bf16(a[mi], b[ni], acc[mi][ni], 0, 0, 0);
        }
        __syncthreads();
    }
    #pragma unroll
    for (int mi = 0; mi < 4; ++mi) {
        #pragma unroll
        for (int ni = 0; ni < 2; ++ni) {
            int col = n0 + wn * 32 + ni * 16 + l16;
            float bv = bias[col];
            #pragma unroll
            for (int r = 0; r < 4; ++r) {
                int row = m0 + wm * 64 + mi * 16 + quad * 4 + r;
                if (row < M) {
                    float v = acc[mi][ni][r] + bv;
                    if (ACT == 1) v = gelu_exact(v);
                    C[(size_t)row * N + col] = tobf(v);
                }
            }
        }
    }
}

// ---------------- fused QKV GEMM, 128-row shape (R14-measured) + bias + RoPE + Q-scale ----
__global__ __launch_bounds__(256) void gemm_qkv128(const bf16* __restrict__ A,
    const bf16* __restrict__ Wqkv, const float* __restrict__ bq,
    const float* __restrict__ bk, const float* __restrict__ bv,
    bf16* __restrict__ qo, bf16* __restrict__ ko, bf16* __restrict__ vo, int M)
{
    const int K = 256, N = 256;
    __shared__ short As[128 * 72];
    __shared__ short Bs[64 * 72];
    int part = blockIdx.y >> 2;
    int n0 = (blockIdx.y & 3) * 64;
    const bf16* W     = Wqkv + (size_t)part * 65536;
    const float* bias = (part == 0) ? bq : (part == 1) ? bk : bv;
    bf16* C           = (part == 0) ? qo : (part == 1) ? ko : vo;
    bool dorope = (part < 2);
    float oscale = (part == 0) ? ATTN_SCALE : 1.0f;

    int tid = threadIdx.x;
    int wave = tid >> 6, lane = tid & 63, quad = lane >> 4, l16 = lane & 15;
    int wm = wave & 1, wn = wave >> 1;
    int m0 = blockIdx.x * 128;

    f32x4_t zero4 = {0.f, 0.f, 0.f, 0.f};
    f32x4_t acc[4][2];
    #pragma unroll
    for (int i = 0; i < 4; ++i) { acc[i][0] = zero4; acc[i][1] = zero4; }

    int srow = tid >> 2, skc = (tid & 3) * 16;
    for (int k0 = 0; k0 < K; k0 += 64) {
        #pragma unroll
        for (int p = 0; p < 2; ++p) {
            int row = srow + p * 64;
            int m = m0 + row;
            bf16x8_t a0 = {}, a1 = {};
            if (m < M) {
                a0 = *(const bf16x8_t*)(A + (size_t)m * K + k0 + skc);
                a1 = *(const bf16x8_t*)(A + (size_t)m * K + k0 + skc + 8);
            }
            *(bf16x8_t*)(&As[row * 72 + skc])     = a0;
            *(bf16x8_t*)(&As[row * 72 + skc + 8]) = a1;
        }
        {
            const bf16* wp = W + (size_t)(n0 + srow) * K + k0 + skc;
            *(bf16x8_t*)(&Bs[srow * 72 + skc])     = *(const bf16x8_t*)(wp);
            *(bf16x8_t*)(&Bs[srow * 72 + skc + 8]) = *(const bf16x8_t*)(wp + 8);
        }
        __syncthreads();
        #pragma unroll
        for (int ks = 0; ks < 2; ++ks) {
            bf16x8_t a[4], b[2];
            #pragma unroll
            for (int mi = 0; mi < 4; ++mi)
                a[mi] = *(bf16x8_t*)(&As[(wm * 64 + mi * 16 + l16) * 72 + ks * 32 + quad * 8]);
            #pragma unroll
            for (int ni = 0; ni < 2; ++ni)
                b[ni] = *(bf16x8_t*)(&Bs[(wn * 32 + ni * 16 + l16) * 72 + ks * 32 + quad * 8]);
            #pragma unroll
            for (int mi = 0; mi < 4; ++mi)
                #pragma unroll
                for (int ni = 0; ni < 2; ++ni)
                    acc[mi][ni] = __builtin_amdgcn_mfma_f32_16x16x32_bf16(a[mi], b[ni], acc[mi][ni], 0, 0, 0);
        }
        __syncthreads();
    }
    int col0 = n0 + wn * 32 + l16;          // d = l16 within this head
    float b1v = bias[col0], b2v = bias[col0 + 16];
    float invf = powf(10000.f, -(float)l16 * (1.f / 16.f));
    #pragma unroll
    for (int mi = 0; mi < 4; ++mi) {
        #pragma unroll
        for (int r = 0; r < 4; ++r) {
            int row = m0 + wm * 64 + mi * 16 + quad * 4 + r;
            if (row >= M) continue;
            int bb = row / S_LEN, t = row - bb * S_LEN;
            float x1 = acc[mi][0][r] + b1v;
            float x2 = acc[mi][1][r] + b2v;
            if (dorope) {
                float ang = (float)t * invf;
                float sn, cs;
                __sincosf(ang, &sn, &cs);
                float y1 = (x1 * cs - x2 * sn) * oscale;
                float y2 = (x1 * sn + x2 * cs) * oscale;
                x1 = y1; x2 = y2;
            }
            size_t obase = ((size_t)bb * S_PAD + t) * N;
            C[obase + col0]      = tobf(x1);
            C[obase + col0 + 16] = tobf(x2);
        }
    }
}

// ---------------- assemble h ----------------
__global__ __launch_bounds__(256) void assemble_h(const bf16* __restrict__ tmp,
    const float* __restrict__ cls, bf16* __restrict__ h)
{
    int row = blockIdx.x;
    int tid = threadIdx.x;
    int b = row / S_LEN, t = row % S_LEN;
    bf16 v = (t == 0) ? tobf(cls[tid]) : tmp[((size_t)(b * 1024 + t - 1)) * E_DIM + tid];
    h[(size_t)row * E_DIM + tid] = v;
}

// ---------------- MFMA flash attention (R17-measured ~48.9 us): 64-key chunks + XCD swizzle ----
__global__ __launch_bounds__(256) void attn_mfma(const bf16* __restrict__ Q,
    const bf16* __restrict__ K, const bf16* __restrict__ V, bf16* __restrict__ O)
{
    __shared__ short VTs[2][32 * 72];     // [buf][d][s], stride 72
    __shared__ short Ps[4][16 * 72];      // [wave][q][s], stride 72
    int blk = blockIdx.x;
    int bh = blk & 63;                    // XCD-locality swizzle
    int qt = blk >> 6;
    int hh = bh & 7, b = bh >> 3;
    int tid = threadIdx.x;
    int wave = tid >> 6, lane = tid & 63, quad = lane >> 4, l16 = lane & 15;
    int q0 = qt * 64 + wave * 16;
    const size_t bSp = (size_t)b * S_PAD;
    const size_t bS  = (size_t)b * S_LEN;
    const size_t hoff = (size_t)hh * HDIM;
    const bf16* Qb = Q + bSp * E_DIM + hoff;
    const bf16* Kb = K + bSp * E_DIM + hoff;
    const bf16* Vb = V + bSp * E_DIM + hoff;

    f32x4_t zero4 = {0.f, 0.f, 0.f, 0.f};
    bf16x8_t qfrag = *(const bf16x8_t*)(Qb + (size_t)(q0 + l16) * E_DIM + quad * 8);
    f32x4_t o0 = zero4, o1 = zero4;
    float lsum[4] = {0.f, 0.f, 0.f, 0.f};

    int vs = tid >> 2, vd = (tid & 3) * 8;   // V staging: 64 s-rows x 32 d
    short* myP = Ps[wave];

    bf16x8_t vpre = *(const bf16x8_t*)(Vb + (size_t)vs * E_DIM + vd);

    for (int c = 0; c < 17; ++c) {
        int s0 = c * 64;
        short* VT = VTs[c & 1];
        #pragma unroll
        for (int j = 0; j < 8; ++j) VT[(vd + j) * 72 + vs] = vpre[j];
        if (c < 16)
            vpre = *(const bf16x8_t*)(Vb + (size_t)(s0 + 64 + vs) * E_DIM + vd);
        f32x4_t sc[4];
        #pragma unroll
        for (int kk = 0; kk < 4; ++kk) {
            bf16x8_t kf = *(const bf16x8_t*)(Kb + (size_t)(s0 + kk * 16 + l16) * E_DIM + quad * 8);
            sc[kk] = __builtin_amdgcn_mfma_f32_16x16x32_bf16(qfrag, kf, zero4, 0, 0, 0);
        }
        #pragma unroll
        for (int r = 0; r < 4; ++r) {
            float ps = 0.f;
            #pragma unroll
            for (int kk = 0; kk < 4; ++kk) {
                int s = s0 + kk * 16 + l16;
                float raw = (s < S_LEN) ? sc[kk][r] : -1e30f;
                float p = __expf(raw);
                ps += p;
                myP[(quad * 4 + r) * 72 + kk * 16 + l16] = bfbits(p);
            }
            lsum[r] += ps;
        }
        __syncthreads();
        #pragma unroll
        for (int half = 0; half < 2; ++half) {
            int off = half * 32 + quad * 8;
            bf16x8_t pf  = *(bf16x8_t*)(&myP[l16 * 72 + off]);
            bf16x8_t vf0 = *(bf16x8_t*)(&VT[l16 * 72 + off]);
            bf16x8_t vf1 = *(bf16x8_t*)(&VT[(16 + l16) * 72 + off]);
            o0 = __builtin_amdgcn_mfma_f32_16x16x32_bf16(pf, vf0, o0, 0, 0, 0);
            o1 = __builtin_amdgcn_mfma_f32_16x16x32_bf16(pf, vf1, o1, 0, 0, 0);
        }
    }
    #pragma unroll
    for (int r = 0; r < 4; ++r) {
        int qrow = q0 + quad * 4 + r;
        if (qrow < S_LEN) {
            float rs = 1.f / row_allsum(lsum[r]);
            O[(bS + qrow) * E_DIM + hoff + l16]      = tobf(o0[r] * rs);
            O[(bS + qrow) * E_DIM + hoff + 16 + l16] = tobf(o1[r] * rs);
        }
    }
}

// ---------------- residual + layernorm: 2 rows per wave (ILP), 8 rows/block ----------------
__global__ __launch_bounds__(256) void ln_kernel(const bf16* __restrict__ X,
    const bf16* __restrict__ R, const float* __restrict__ g,
    const float* __restrict__ b, bf16* __restrict__ out)
{
    int wave = threadIdx.x >> 6, lane = threadIdx.x & 63;
    int row0 = blockIdx.x * 8 + wave * 2;
    size_t base0 = (size_t)row0 * E_DIM + lane * 4;
    size_t base1 = base0 + E_DIM;
    float v0[4], v1[4];
    {
        bf16x4_t xa = *(const bf16x4_t*)(X + base0);
        bf16x4_t xb = *(const bf16x4_t*)(X + base1);
        #pragma unroll
        for (int i = 0; i < 4; ++i) {
            bf16 t; short s;
            s = xa[i]; __builtin_memcpy(&t, &s, 2); v0[i] = bf(t);
            s = xb[i]; __builtin_memcpy(&t, &s, 2); v1[i] = bf(t);
        }
    }
    if (R) {
        bf16x4_t ra = *(const bf16x4_t*)(R + base0);
        bf16x4_t rb = *(const bf16x4_t*)(R + base1);
        #pragma unroll
        for (int i = 0; i < 4; ++i) {
            bf16 t; short s;
            s = ra[i]; __builtin_memcpy(&t, &s, 2); v0[i] += bf(t);
            s = rb[i]; __builtin_memcpy(&t, &s, 2); v1[i] += bf(t);
        }
    }
    float s0 = v0[0] + v0[1] + v0[2] + v0[3];
    float s1 = v1[0] + v1[1] + v1[2] + v1[3];
    #pragma unroll
    for (int off = 32; off; off >>= 1) { s0 += __shfl_xor(s0, off); s1 += __shfl_xor(s1, off); }
    float m0 = s0 * (1.f / 256.f), m1 = s1 * (1.f / 256.f);
    float w0 = 0.f, w1 = 0.f;
    #pragma unroll
    for (int i = 0; i < 4; ++i) {
        v0[i] -= m0; w0 += v0[i] * v0[i];
        v1[i] -= m1; w1 += v1[i] * v1[i];
    }
    #pragma unroll
    for (int off = 32; off; off >>= 1) { w0 += __shfl_xor(w0, off); w1 += __shfl_xor(w1, off); }
    float r0 = rsqrtf(w0 * (1.f / 256.f) + EPS_LN);
    float r1 = rsqrtf(w1 * (1.f / 256.f) + EPS_LN);
    int c = lane * 4;
    bf16x4_t oa, ob;
    #pragma unroll
    for (int i = 0; i < 4; ++i) {
        oa[i] = bfbits(v0[i] * r0 * g[c + i] + b[c + i]);
        ob[i] = bfbits(v1[i] * r1 * g[c + i] + b[c + i]);
    }
    *(bf16x4_t*)(out + base0) = oa;
    *(bf16x4_t*)(out + base1) = ob;
}

// ---------------- final head ----------------
__global__ __launch_bounds__(256) void ts_kernel(const bf16* __restrict__ H,
    const float* __restrict__ w, const float* __restrict__ tb,
    float* __restrict__ out)
{
    int wid = (blockIdx.x << 2) + (threadIdx.x >> 6);
    int lane = threadIdx.x & 63;
    int b = wid >> 10, t = wid & 1023;
    const bf16* row = H + ((size_t)(b * S_LEN + t + 1)) * E_DIM;
    float acc = 0.f;
    for (int e = lane; e < E_DIM; e += 64) acc += bf(row[e]) * w[e];
    #pragma unroll
    for (int off = 32; off; off >>= 1) acc += __shfl_down(acc, off, 64);
    if (lane == 0) out[wid] = acc + tb[0];
}

// ---------------- host launch ----------------
extern "C" void kernel_launch(void* const* d_in, const int* in_sizes, int n_in,
                              void* d_out, int out_size, void* d_ws, size_t ws_size,
                              hipStream_t stream)
{
    (void)in_sizes; (void)n_in; (void)out_size; (void)ws_size;
    const float* X        = (const float*)d_in[0];
    const float* CONV1_DW = (const float*)d_in[1];
    const float* CONV1_PW = (const float*)d_in[2];
    const float* BN1_G    = (const float*)d_in[3];
    const float* BN1_B    = (const float*)d_in[4];
    const float* CONV2_DW = (const float*)d_in[5];
    const float* CONV2_PW = (const float*)d_in[6];
    const float* BN2_G    = (const float*)d_in[7];
    const float* BN2_B    = (const float*)d_in[8];
    const float* PROJ_W   = (const float*)d_in[9];
    const float* PROJ_B   = (const float*)d_in[10];
    const float* CLS      = (const float*)d_in[11];
    const float* WQ       = (const float*)d_in[12];
    const float* BQ       = (const float*)d_in[13];
    const float* WK       = (const float*)d_in[14];
    const float* BK       = (const float*)d_in[15];
    const float* WV       = (const float*)d_in[16];
    const float* BV       = (const float*)d_in[17];
    const float* WO       = (const float*)d_in[18];
    const float* BO       = (const float*)d_in[19];
    const float* LN1G     = (const float*)d_in[20];
    const float* LN1B     = (const float*)d_in[21];
    const float* W1       = (const float*)d_in[22];
    const float* B1       = (const float*)d_in[23];
    const float* W2       = (const float*)d_in[24];
    const float* B2       = (const float*)d_in[25];
    const float* LN2G     = (const float*)d_in[26];
    const float* LN2B     = (const float*)d_in[27];
    const float* LATW     = (const float*)d_in[28];
    const float* LATB     = (const float*)d_in[29];
    const float* LATNG    = (const float*)d_in[30];
    const float* LATNB    = (const float*)d_in[31];
    const float* TSW      = (const float*)d_in[32];
    const float* TSB      = (const float*)d_in[33];

    const size_t SROW  = (size_t)MROWS * E_DIM;       // 2,099,200
    const size_t SPROW = (size_t)8 * S_PAD * E_DIM;   // 2,228,224 (padded q/k/v)
    bf16* h    = (bf16*)d_ws;
    bf16* bufB = h + SROW;
    bf16* r0   = bufB + SROW;
    bf16* q  = r0;                     // padded stride S_PAD per batch
    bf16* k  = r0 + SPROW;
    bf16* v  = r0 + 2 * SPROW;
    bf16* cx = r0 + 3 * SPROW;         // compact (SROW)
    bf16* wall = cx + SROW;            // 6 layer slots, 6*WSLOT elems
    bf16* pslot = wall + 6 * WSLOT;    // proj/lat slot (65536 elems)
    bf16* y1 = r0;
    bf16* y2 = r0 + SROW;
    bf16* mid = r0;                    // MLP hidden 4*SROW <= r0 region size

    conv_sep1<<<dim3(512), dim3(256), 0, stream>>>(X, CONV1_DW, CONV1_PW, BN1_G, BN1_B, y1);
    conv_sep2<<<dim3(256), dim3(256), 0, stream>>>(y1, CONV2_DW, CONV2_PW, BN2_G, BN2_B, y2);
    cvt_w<<<dim3(32), dim3(256), 0, stream>>>(PROJ_W, pslot, 32768);
    gemm_bf<0><<<dim3(128, 4), dim3(256), 0, stream>>>(y2, pslot, PROJ_B, bufB, 8192, 256, 128);
    assemble_h<<<dim3(MROWS), dim3(256), 0, stream>>>(bufB, CLS, h);
    // convert all six layers' weights in ONE dispatch
    cvt_layer6<<<dim3(768, 6), dim3(256), 0, stream>>>(WQ, WK, WV, WO, W1, W2, wall);

    for (int l = 0; l < 6; ++l) {
        bf16* wslot = wall + (size_t)l * WSLOT;
        gemm_qkv128<<<dim3(65, 12), dim3(256), 0, stream>>>(h, wslot,
            BQ + l * 256, BK + l * 256, BV + l * 256, q, k, v, MROWS);
        attn_mfma<<<dim3(64 * 17), dim3(256), 0, stream>>>(q, k, v, cx);
        gemm_bf<0><<<dim3(129, 4), dim3(256), 0, stream>>>(cx, wslot + 196608, BO + l * 256, bufB, MROWS, 256, 256);
        ln_kernel<<<dim3(MROWS / 8), dim3(256), 0, stream>>>(h, bufB, LN1G + l * 256, LN1B + l * 256, h);
        gemm_bf128<1><<<dim3(65, 16), dim3(256), 0, stream>>>(h, wslot + 262144, B1 + l * 1024, mid, MROWS, 1024, 256);
        gemm_bf<0><<<dim3(129, 4), dim3(256), 0, stream>>>(mid, wslot + 524288, B2 + l * 256, bufB, MROWS, 256, 1024);
        ln_kernel<<<dim3(MROWS / 8), dim3(256), 0, stream>>>(h, bufB, LN2G + l * 256, LN2B + l * 256, h);
    }

    cvt_w<<<dim3(64), dim3(256), 0, stream>>>(LATW, pslot, 65536);
    gemm_bf<0><<<dim3(129, 4), dim3(256), 0, stream>>>(h, pslot, LATB, bufB, MROWS, 256, 256);
    ln_kernel<<<dim3(MROWS / 8), dim3(256), 0, stream>>>(bufB, nullptr, LATNG, LATNB, r0);
    ts_kernel<<<dim3(2048), dim3(256), 0, stream>>>(r0, TSW, TSB, (float*)d_out);
}